// Round 1
// baseline (200.467 us; speedup 1.0000x reference)
//
#include <hip/hip_runtime.h>
#include <hip/hip_bf16.h>

#define NTOK 4096
#define BATCH 8
#define NROWS (BATCH * NTOK)   // 32768

typedef __attribute__((ext_vector_type(8))) short bfx8;
typedef __attribute__((ext_vector_type(4))) short bfx4;
typedef __attribute__((ext_vector_type(4))) float f32x4;

__device__ __forceinline__ short f2bf(float f) {
    unsigned u = __builtin_bit_cast(unsigned, f);
    u += 0x7fffu + ((u >> 16) & 1u);
    return (short)(u >> 16);
}

#define GLDS16(gp, lp)                                                            \
    __builtin_amdgcn_global_load_lds(                                             \
        (const __attribute__((address_space(1))) void*)(gp),                      \
        (__attribute__((address_space(3))) void*)(lp), 16, 0, 0)

// ---------------- weight prep: WT[co][ci] = bf16(scale * g[ci] * W[ci][co]),
// ---------------- b'[co] = scale * (bias[co] + sum_ci be[ci]*W[ci][co])
__global__ __launch_bounds__(256) void prep_w(
    const float* __restrict__ Wq, const float* __restrict__ Wk,
    const float* __restrict__ Wv, const float* __restrict__ Wp,
    const float* __restrict__ qg, const float* __restrict__ qb,
    const float* __restrict__ kg, const float* __restrict__ kb,
    const float* __restrict__ vg, const float* __restrict__ vb,
    const float* __restrict__ bq, const float* __restrict__ bk,
    const float* __restrict__ bv, const float* __restrict__ bp,
    short* __restrict__ wt, float* __restrict__ bb) {
    int m = blockIdx.x;
    const float *W, *g, *be, *bias;
    float scale = 1.0f;
    if (m == 0)      { W = Wq; g = qg; be = qb; bias = bq; scale = 0.17677669529663687f; }
    else if (m == 1) { W = Wk; g = kg; be = kb; bias = bk; }
    else if (m == 2) { W = Wv; g = vg; be = vb; bias = bv; }
    else             { W = Wp; g = nullptr; be = nullptr; bias = bp; }
    int co = threadIdx.x;
    short* WT = wt + m * 65536;
    float acc = bias[co];
    for (int ci = 0; ci < 256; ci++) {
        float w = W[ci * 256 + co];
        float gg = g ? g[ci] : 1.0f;
        WT[co * 256 + ci] = f2bf(scale * gg * w);
        if (be) acc += be[ci] * w;
    }
    bb[m * 256 + co] = scale * acc;
}

// ---------------- LN over contiguous rows (cva): one wave per row ----------------
__global__ __launch_bounds__(256) void ln_rows(const float* __restrict__ src,
                                               short* __restrict__ dst) {
    int row = blockIdx.x * 4 + (threadIdx.x >> 6);
    int lane = threadIdx.x & 63;
    const float4 v = *reinterpret_cast<const float4*>(src + (size_t)row * 256 + lane * 4);
    float s = v.x + v.y + v.z + v.w;
    float q = v.x * v.x + v.y * v.y + v.z * v.z + v.w * v.w;
#pragma unroll
    for (int m = 1; m < 64; m <<= 1) { s += __shfl_xor(s, m); q += __shfl_xor(q, m); }
    float mean = s * (1.0f / 256.0f);
    float var  = q * (1.0f / 256.0f) - mean * mean;
    float rstd = rsqrtf(var + 1e-5f);
    bfx4 o;
    o[0] = f2bf((v.x - mean) * rstd);
    o[1] = f2bf((v.y - mean) * rstd);
    o[2] = f2bf((v.z - mean) * rstd);
    o[3] = f2bf((v.w - mean) * rstd);
    *reinterpret_cast<bfx4*>(dst + (size_t)row * 256 + lane * 4) = o;
}

// ---------------- LN over transposed view xs[b,n,c] = x[b,c,n] ----------------
__global__ __launch_bounds__(256) void ln_tr(const float* __restrict__ x,
                                             short* __restrict__ dst) {
    int b = blockIdx.x >> 6;
    int n0 = (blockIdx.x & 63) * 64;
    __shared__ float tile[256][65];
    int t = threadIdx.x;
    int nl = t & 63, cq = t >> 6;
    const float* xb = x + (size_t)b * 256 * 4096 + n0;
    for (int c0 = 0; c0 < 256; c0 += 4)
        tile[c0 + cq][nl] = xb[(size_t)(c0 + cq) * 4096 + nl];
    __syncthreads();
    int n = t >> 2, j = t & 3;
    float s = 0.f, q = 0.f;
    for (int c = j; c < 256; c += 4) { float v = tile[c][n]; s += v; q += v * v; }
    s += __shfl_xor(s, 1); s += __shfl_xor(s, 2);
    q += __shfl_xor(q, 1); q += __shfl_xor(q, 2);
    float mean = s * (1.0f / 256.0f);
    float var  = q * (1.0f / 256.0f) - mean * mean;
    float rstd = rsqrtf(var + 1e-5f);
    short* drow = dst + (size_t)(b * 4096 + n0 + n) * 256;
    for (int c0 = j * 64; c0 < (j + 1) * 64; c0 += 8) {
        bfx8 o;
#pragma unroll
        for (int jj = 0; jj < 8; jj++) o[jj] = f2bf((tile[c0 + jj][n] - mean) * rstd);
        *reinterpret_cast<bfx8*>(drow + c0) = o;
    }
}

// ---------------- GEMM: out[M,256] = A[M,256](bf16) @ WT^T + bias ----------------
// MODE 0: bf16 out [M,256].  MODE 1: fp32 out written transposed as [B,C,N].
template <int MODE>
__global__ __launch_bounds__(256) void gemm_bt(const short* __restrict__ A,
                                               const short* __restrict__ WT,
                                               const float* __restrict__ bias,
                                               void* __restrict__ outp) {
    __shared__ short As[128 * 64];
    __shared__ short Bs[128 * 64];
    __shared__ float tr[MODE ? 4 * 16 * 65 : 4];
    int t = threadIdx.x;
    int w = t >> 6, l = t & 63;
    int c = l & 15, g = l >> 4;
    int row0 = blockIdx.x * 128;
    int col0 = blockIdx.y * 128;
    int wr = w >> 1, wc = w & 1;
    f32x4 acc[4][4] = {};
    const short* Ag = A + (size_t)row0 * 256;
    const short* Bg = WT + (size_t)col0 * 256;
    int srow = w * 8 + (l >> 3);
    int sk = (l & 7) * 8;
    for (int kt = 0; kt < 4; kt++) {
        __syncthreads();
#pragma unroll
        for (int i = 0; i < 4; i++)
            GLDS16(Ag + (size_t)(i * 32 + srow) * 256 + kt * 64 + sk, As + i * 2048 + w * 512);
#pragma unroll
        for (int i = 0; i < 4; i++)
            GLDS16(Bg + (size_t)(i * 32 + srow) * 256 + kt * 64 + sk, Bs + i * 2048 + w * 512);
        __syncthreads();
#pragma unroll
        for (int ks = 0; ks < 2; ks++) {
            bfx8 af[4], bf[4];
#pragma unroll
            for (int m = 0; m < 4; m++)
                af[m] = *reinterpret_cast<const bfx8*>(As + (wr * 64 + m * 16 + c) * 64 + ks * 32 + g * 8);
#pragma unroll
            for (int n = 0; n < 4; n++)
                bf[n] = *reinterpret_cast<const bfx8*>(Bs + (wc * 64 + n * 16 + c) * 64 + ks * 32 + g * 8);
#pragma unroll
            for (int m = 0; m < 4; m++)
#pragma unroll
                for (int n = 0; n < 4; n++)
                    acc[m][n] = __builtin_amdgcn_mfma_f32_16x16x32_bf16(af[m], bf[n], acc[m][n], 0, 0, 0);
        }
    }
    if (MODE == 0) {
        short* out = (short*)outp;
#pragma unroll
        for (int m = 0; m < 4; m++)
#pragma unroll
            for (int n = 0; n < 4; n++)
#pragma unroll
                for (int j = 0; j < 4; j++) {
                    int r = row0 + wr * 64 + m * 16 + g * 4 + j;
                    int col = col0 + wc * 64 + n * 16 + c;
                    out[(size_t)r * 256 + col] = f2bf(acc[m][n][j] + bias[col]);
                }
    } else {
        float* out = (float*)outp;
        float* tw = tr + w * (16 * 65);
        int rbase = row0 + wr * 64;
        int bidx = rbase >> 12;
        int nn = rbase & 4095;
        float* outb = out + (size_t)bidx * 1048576 + nn;
#pragma unroll
        for (int p = 0; p < 4; p++) {
#pragma unroll
            for (int m = 0; m < 4; m++)
#pragma unroll
                for (int j = 0; j < 4; j++)
                    tw[c * 65 + m * 16 + g * 4 + j] =
                        acc[m][p][j] + bias[col0 + wc * 64 + p * 16 + c];
            __builtin_amdgcn_s_waitcnt(0);  // drain lgkm before cross-lane read
#pragma unroll
            for (int cl = 0; cl < 16; cl++) {
                int co = col0 + wc * 64 + p * 16 + cl;
                outb[(size_t)co * 4096 + l] = tw[cl * 65 + l];
            }
            __builtin_amdgcn_s_waitcnt(0);
        }
    }
}

// ---------------- block-local attention: one wave per (b, h, chunk) ----------------
__global__ __launch_bounds__(64) void attn(const short* __restrict__ q,
                                           const short* __restrict__ k,
                                           const short* __restrict__ v,
                                           short* __restrict__ o) {
    int id = blockIdx.x;
    int b = id >> 9, h = (id >> 6) & 7, ch = id & 63;
    size_t base = (size_t)(b * 4096 + ch * 64) * 256 + h * 32;
    const short* qb = q + base;
    const short* kb = k + base;
    const short* vb = v + base;
    short* ob = o + base;
    int l = threadIdx.x, c = l & 15, g = l >> 4;

    __shared__ short Vs[64 * 32];
    __shared__ short P[64 * 80];

    bfx8 qf[4], kf[4];
#pragma unroll
    for (int m = 0; m < 4; m++)
        qf[m] = *reinterpret_cast<const bfx8*>(qb + (size_t)(m * 16 + c) * 256 + g * 8);
#pragma unroll
    for (int n = 0; n < 4; n++)
        kf[n] = *reinterpret_cast<const bfx8*>(kb + (size_t)(n * 16 + c) * 256 + g * 8);

    // stage V tile [64 kv][32 d] into LDS (coalesced 16B chunks)
    {
        int kv = l >> 2, d8 = (l & 3) * 8;
#pragma unroll
        for (int it = 0; it < 4; it++) {
            bfx8 tv = *reinterpret_cast<const bfx8*>(vb + (size_t)(it * 16 + kv) * 256 + d8);
            *reinterpret_cast<bfx8*>(&Vs[(it * 16 + kv) * 32 + d8]) = tv;
        }
    }

    f32x4 s[4][4] = {};
#pragma unroll
    for (int m = 0; m < 4; m++)
#pragma unroll
        for (int n = 0; n < 4; n++)
            s[m][n] = __builtin_amdgcn_mfma_f32_16x16x32_bf16(qf[m], kf[n], s[m][n], 0, 0, 0);

    // wave-parallel softmax over 64 keys (cols = 4 n-tiles x 16 lanes)
    float rs[4][4];
#pragma unroll
    for (int m = 0; m < 4; m++)
#pragma unroll
        for (int j = 0; j < 4; j++) {
            float mx = fmaxf(fmaxf(s[m][0][j], s[m][1][j]), fmaxf(s[m][2][j], s[m][3][j]));
            mx = fmaxf(mx, __shfl_xor(mx, 1));
            mx = fmaxf(mx, __shfl_xor(mx, 2));
            mx = fmaxf(mx, __shfl_xor(mx, 4));
            mx = fmaxf(mx, __shfl_xor(mx, 8));
            float sum = 0.f;
#pragma unroll
            for (int n = 0; n < 4; n++) {
                float e = __expf(s[m][n][j] - mx);
                s[m][n][j] = e;
                sum += e;
            }
            sum += __shfl_xor(sum, 1);
            sum += __shfl_xor(sum, 2);
            sum += __shfl_xor(sum, 4);
            sum += __shfl_xor(sum, 8);
            rs[m][j] = 1.0f / sum;
        }

    // P (unnormalized, <=1) to LDS in row-major [64][pitch 80]
#pragma unroll
    for (int m = 0; m < 4; m++)
#pragma unroll
        for (int n = 0; n < 4; n++)
#pragma unroll
            for (int j = 0; j < 4; j++)
                P[(m * 16 + g * 4 + j) * 80 + n * 16 + c] = f2bf(s[m][n][j]);
    __syncthreads();

    // O = P @ V  (K = 64 keys in two 32-slices)
    f32x4 oacc[4][2] = {};
#pragma unroll
    for (int ks = 0; ks < 2; ks++) {
        bfx8 vf[2];
#pragma unroll
        for (int n2 = 0; n2 < 2; n2++)
#pragma unroll
            for (int j = 0; j < 8; j++)
                vf[n2][j] = Vs[(ks * 32 + g * 8 + j) * 32 + n2 * 16 + c];
#pragma unroll
        for (int m = 0; m < 4; m++) {
            bfx8 pf = *reinterpret_cast<const bfx8*>(&P[(m * 16 + c) * 80 + ks * 32 + g * 8]);
#pragma unroll
            for (int n2 = 0; n2 < 2; n2++)
                oacc[m][n2] = __builtin_amdgcn_mfma_f32_16x16x32_bf16(pf, vf[n2], oacc[m][n2], 0, 0, 0);
        }
    }
#pragma unroll
    for (int m = 0; m < 4; m++)
#pragma unroll
        for (int n2 = 0; n2 < 2; n2++)
#pragma unroll
            for (int j = 0; j < 4; j++)
                ob[(size_t)(m * 16 + g * 4 + j) * 256 + n2 * 16 + c] =
                    f2bf(oacc[m][n2][j] * rs[m][j]);
}

extern "C" void kernel_launch(void* const* d_in, const int* in_sizes, int n_in,
                              void* d_out, int out_size, void* d_ws, size_t ws_size,
                              hipStream_t stream) {
    const float* x   = (const float*)d_in[0];
    const float* cva = (const float*)d_in[1];
    const float* qg  = (const float*)d_in[2];
    const float* qb  = (const float*)d_in[3];
    const float* kg  = (const float*)d_in[4];
    const float* kb  = (const float*)d_in[5];
    const float* vg  = (const float*)d_in[6];
    const float* vb  = (const float*)d_in[7];
    const float* Wq  = (const float*)d_in[8];
    const float* bq  = (const float*)d_in[9];
    const float* Wk  = (const float*)d_in[10];
    const float* bk  = (const float*)d_in[11];
    const float* Wv  = (const float*)d_in[12];
    const float* bv  = (const float*)d_in[13];
    const float* Wp  = (const float*)d_in[14];
    const float* bp  = (const float*)d_in[15];
    float* out = (float*)d_out;
    char* ws = (char*)d_ws;

    const size_t SEG = (size_t)NROWS * 256 * 2;  // 16 MB bf16 [32768,256]
    short* cva_hat = (short*)(ws);
    short* xs_hat  = (short*)(ws + SEG);
    short* qm      = (short*)(ws + 2 * SEG);
    short* km      = (short*)(ws + 3 * SEG);
    short* vm      = (short*)(ws + 4 * SEG);
    short* om      = cva_hat;  // reused after q/k GEMMs consume cva_hat
    short* wt      = (short*)(ws + 5 * SEG);
    float* bb      = (float*)(ws + 5 * SEG + 4 * 65536 * sizeof(short));

    prep_w<<<4, 256, 0, stream>>>(Wq, Wk, Wv, Wp, qg, qb, kg, kb, vg, vb,
                                  bq, bk, bv, bp, wt, bb);
    ln_rows<<<NROWS / 4, 256, 0, stream>>>(cva, cva_hat);
    ln_tr<<<512, 256, 0, stream>>>(x, xs_hat);

    dim3 gg(NROWS / 128, 2);
    gemm_bt<0><<<gg, 256, 0, stream>>>(cva_hat, wt + 0 * 65536, bb + 0,   qm);
    gemm_bt<0><<<gg, 256, 0, stream>>>(cva_hat, wt + 1 * 65536, bb + 256, km);
    gemm_bt<0><<<gg, 256, 0, stream>>>(xs_hat,  wt + 2 * 65536, bb + 512, vm);

    attn<<<BATCH * 8 * 64, 64, 0, stream>>>(qm, km, vm, om);

    gemm_bt<1><<<gg, 256, 0, stream>>>(om, wt + 3 * 65536, bb + 768, out);
}

// Round 2
// 108.142 us; speedup vs baseline: 1.8537x; 1.8537x over previous
//
#include <hip/hip_runtime.h>
#include <hip/hip_bf16.h>

#define NTOK 4096
#define BATCH 8
#define NROWS (BATCH * NTOK)   // 32768

typedef __attribute__((ext_vector_type(8))) short bfx8;
typedef __attribute__((ext_vector_type(4))) short bfx4;
typedef __attribute__((ext_vector_type(4))) float f32x4;

__device__ __forceinline__ short f2bf(float f) {
    unsigned u = __builtin_bit_cast(unsigned, f);
    u += 0x7fffu + ((u >> 16) & 1u);
    return (short)(u >> 16);
}

#define GLDS16(gp, lp)                                                            \
    __builtin_amdgcn_global_load_lds(                                             \
        (const __attribute__((address_space(1))) void*)(gp),                      \
        (__attribute__((address_space(3))) void*)(lp), 16, 0, 0)

// ---------------- weight prep: WT[co][ci] = bf16(scale * g[ci] * W[ci][co])
// grid (4 matrices, 16 ci-slices) x 256 threads. Also emits per-block bias
// partials sum_ci be[ci]*W[ci][co] for the LN-beta fold (reduced in prep_b).
__global__ __launch_bounds__(256) void prep_w(
    const float* __restrict__ Wq, const float* __restrict__ Wk,
    const float* __restrict__ Wv, const float* __restrict__ Wp,
    const float* __restrict__ qg, const float* __restrict__ qb,
    const float* __restrict__ kg, const float* __restrict__ kb,
    const float* __restrict__ vg, const float* __restrict__ vb,
    short* __restrict__ wt, float* __restrict__ bbp) {
    int m = blockIdx.x;
    int ci0 = blockIdx.y * 16;
    const float *W, *g, *be;
    float scale = 1.0f;
    if (m == 0)      { W = Wq; g = qg; be = qb; scale = 0.17677669529663687f; }
    else if (m == 1) { W = Wk; g = kg; be = kb; }
    else if (m == 2) { W = Wv; g = vg; be = vb; }
    else             { W = Wp; g = nullptr; be = nullptr; }
    __shared__ float tile[16][257];
    int t = threadIdx.x;
#pragma unroll
    for (int i = 0; i < 16; i++)
        tile[i][t] = W[(size_t)(ci0 + i) * 256 + t];
    __syncthreads();
    float p = 0.f;
    if (be) {
#pragma unroll
        for (int i = 0; i < 16; i++) p += be[ci0 + i] * tile[i][t];
    }
    bbp[(m * 16 + blockIdx.y) * 256 + t] = p;
    short* WT = wt + m * 65536 + t * 256 + ci0;
    bfx8 o0, o1;
#pragma unroll
    for (int j = 0; j < 8; j++) {
        float gv = g ? g[ci0 + j] : 1.0f;
        o0[j] = f2bf(scale * gv * tile[j][t]);
    }
#pragma unroll
    for (int j = 0; j < 8; j++) {
        float gv = g ? g[ci0 + 8 + j] : 1.0f;
        o1[j] = f2bf(scale * gv * tile[8 + j][t]);
    }
    *reinterpret_cast<bfx8*>(WT) = o0;
    *reinterpret_cast<bfx8*>(WT + 8) = o1;
}

// ---------------- bias reduce: bb[m][co] = scale*(bias[co] + sum partials) ----------------
__global__ __launch_bounds__(256) void prep_b(
    const float* __restrict__ bq, const float* __restrict__ bk,
    const float* __restrict__ bv, const float* __restrict__ bp,
    const float* __restrict__ bbp, float* __restrict__ bb) {
    int m = blockIdx.x, t = threadIdx.x;
    const float* bias = (m == 0) ? bq : (m == 1) ? bk : (m == 2) ? bv : bp;
    float scale = (m == 0) ? 0.17677669529663687f : 1.0f;
    float s = bias[t];
#pragma unroll
    for (int i = 0; i < 16; i++) s += bbp[(m * 16 + i) * 256 + t];
    bb[m * 256 + t] = scale * s;
}

// ---------------- LN over contiguous rows (cva): one wave per row ----------------
__global__ __launch_bounds__(256) void ln_rows(const float* __restrict__ src,
                                               short* __restrict__ dst) {
    int row = blockIdx.x * 4 + (threadIdx.x >> 6);
    int lane = threadIdx.x & 63;
    const float4 v = *reinterpret_cast<const float4*>(src + (size_t)row * 256 + lane * 4);
    float s = v.x + v.y + v.z + v.w;
    float q = v.x * v.x + v.y * v.y + v.z * v.z + v.w * v.w;
#pragma unroll
    for (int m = 1; m < 64; m <<= 1) { s += __shfl_xor(s, m); q += __shfl_xor(q, m); }
    float mean = s * (1.0f / 256.0f);
    float var  = q * (1.0f / 256.0f) - mean * mean;
    float rstd = rsqrtf(var + 1e-5f);
    bfx4 o;
    o[0] = f2bf((v.x - mean) * rstd);
    o[1] = f2bf((v.y - mean) * rstd);
    o[2] = f2bf((v.z - mean) * rstd);
    o[3] = f2bf((v.w - mean) * rstd);
    *reinterpret_cast<bfx4*>(dst + (size_t)row * 256 + lane * 4) = o;
}

// ---------------- LN over transposed view xs[b,n,c] = x[b,c,n] ----------------
__global__ __launch_bounds__(256) void ln_tr(const float* __restrict__ x,
                                             short* __restrict__ dst) {
    int b = blockIdx.x >> 6;
    int n0 = (blockIdx.x & 63) * 64;
    __shared__ float tile[256][65];
    int t = threadIdx.x;
    int nl = t & 63, cq = t >> 6;
    const float* xb = x + (size_t)b * 256 * 4096 + n0;
    for (int c0 = 0; c0 < 256; c0 += 4)
        tile[c0 + cq][nl] = xb[(size_t)(c0 + cq) * 4096 + nl];
    __syncthreads();
    int n = t >> 2, j = t & 3;
    float s = 0.f, q = 0.f;
    for (int c = j; c < 256; c += 4) { float v = tile[c][n]; s += v; q += v * v; }
    s += __shfl_xor(s, 1); s += __shfl_xor(s, 2);
    q += __shfl_xor(q, 1); q += __shfl_xor(q, 2);
    float mean = s * (1.0f / 256.0f);
    float var  = q * (1.0f / 256.0f) - mean * mean;
    float rstd = rsqrtf(var + 1e-5f);
    short* drow = dst + (size_t)(b * 4096 + n0 + n) * 256;
    for (int c0 = j * 64; c0 < (j + 1) * 64; c0 += 8) {
        bfx8 o;
#pragma unroll
        for (int jj = 0; jj < 8; jj++) o[jj] = f2bf((tile[c0 + jj][n] - mean) * rstd);
        *reinterpret_cast<bfx8*>(drow + c0) = o;
    }
}

// ---------------- GEMM: out[M,OS-subset] = A[M,256](bf16) @ WT^T + bias ----------------
// MODE 0: bf16 out [M, ostride], cols col0..col0+128.  MODE 1: fp32 out as [B,C,N].
template <int MODE>
__global__ __launch_bounds__(256) void gemm_bt(const short* __restrict__ A,
                                               const short* __restrict__ WT,
                                               const float* __restrict__ bias,
                                               void* __restrict__ outp,
                                               int ostride) {
    __shared__ short As[128 * 64];
    __shared__ short Bs[128 * 64];
    __shared__ float tr[MODE ? 4 * 16 * 65 : 4];
    int t = threadIdx.x;
    int w = t >> 6, l = t & 63;
    int c = l & 15, g = l >> 4;
    int row0 = blockIdx.x * 128;
    int col0 = blockIdx.y * 128;
    int wr = w >> 1, wc = w & 1;
    f32x4 acc[4][4] = {};
    const short* Ag = A + (size_t)row0 * 256;
    const short* Bg = WT + (size_t)col0 * 256;
    int srow = w * 8 + (l >> 3);
    int sk = (l & 7) * 8;
    for (int kt = 0; kt < 4; kt++) {
        __syncthreads();
#pragma unroll
        for (int i = 0; i < 4; i++)
            GLDS16(Ag + (size_t)(i * 32 + srow) * 256 + kt * 64 + sk, As + i * 2048 + w * 512);
#pragma unroll
        for (int i = 0; i < 4; i++)
            GLDS16(Bg + (size_t)(i * 32 + srow) * 256 + kt * 64 + sk, Bs + i * 2048 + w * 512);
        __syncthreads();
#pragma unroll
        for (int ks = 0; ks < 2; ks++) {
            bfx8 af[4], bf[4];
#pragma unroll
            for (int m = 0; m < 4; m++)
                af[m] = *reinterpret_cast<const bfx8*>(As + (wr * 64 + m * 16 + c) * 64 + ks * 32 + g * 8);
#pragma unroll
            for (int n = 0; n < 4; n++)
                bf[n] = *reinterpret_cast<const bfx8*>(Bs + (wc * 64 + n * 16 + c) * 64 + ks * 32 + g * 8);
#pragma unroll
            for (int m = 0; m < 4; m++)
#pragma unroll
                for (int n = 0; n < 4; n++)
                    acc[m][n] = __builtin_amdgcn_mfma_f32_16x16x32_bf16(af[m], bf[n], acc[m][n], 0, 0, 0);
        }
    }
    if (MODE == 0) {
        short* out = (short*)outp;
#pragma unroll
        for (int m = 0; m < 4; m++)
#pragma unroll
            for (int n = 0; n < 4; n++)
#pragma unroll
                for (int j = 0; j < 4; j++) {
                    int r = row0 + wr * 64 + m * 16 + g * 4 + j;
                    int col = col0 + wc * 64 + n * 16 + c;
                    out[(size_t)r * ostride + col] = f2bf(acc[m][n][j] + bias[col]);
                }
    } else {
        float* out = (float*)outp;
        float* tw = tr + w * (16 * 65);
        int rbase = row0 + wr * 64;
        int bidx = rbase >> 12;
        int nn = rbase & 4095;
        float* outb = out + (size_t)bidx * 1048576 + nn;
#pragma unroll
        for (int p = 0; p < 4; p++) {
#pragma unroll
            for (int m = 0; m < 4; m++)
#pragma unroll
                for (int j = 0; j < 4; j++)
                    tw[c * 65 + m * 16 + g * 4 + j] =
                        acc[m][p][j] + bias[col0 + wc * 64 + p * 16 + c];
            __builtin_amdgcn_s_waitcnt(0);  // drain lds writes before cross-lane read
#pragma unroll
            for (int cl = 0; cl < 16; cl++) {
                int co = col0 + wc * 64 + p * 16 + cl;
                outb[(size_t)co * 4096 + l] = tw[cl * 65 + l];
            }
            __builtin_amdgcn_s_waitcnt(0);
        }
    }
}

// ---------------- block-local attention: one wave per (b, h, chunk) ----------------
// q,k live in merged qk buffer [32768][512] (q cols 0..255, k cols 256..511).
__global__ __launch_bounds__(64) void attn(const short* __restrict__ qk,
                                           const short* __restrict__ v,
                                           short* __restrict__ o) {
    int id = blockIdx.x;
    int b = id >> 9, h = (id >> 6) & 7, ch = id & 63;
    int r0 = b * 4096 + ch * 64;
    const short* qb = qk + (size_t)r0 * 512 + h * 32;
    const short* kb = qb + 256;
    const short* vb = v + (size_t)r0 * 256 + h * 32;
    short* ob = o + (size_t)r0 * 256 + h * 32;
    int l = threadIdx.x, c = l & 15, g = l >> 4;

    __shared__ short Vs[64 * 32];
    __shared__ short P[64 * 80];

    bfx8 qf[4], kf[4];
#pragma unroll
    for (int m = 0; m < 4; m++)
        qf[m] = *reinterpret_cast<const bfx8*>(qb + (size_t)(m * 16 + c) * 512 + g * 8);
#pragma unroll
    for (int n = 0; n < 4; n++)
        kf[n] = *reinterpret_cast<const bfx8*>(kb + (size_t)(n * 16 + c) * 512 + g * 8);

    // stage V tile [64 kv][32 d] into LDS (coalesced 16B chunks)
    {
        int kv = l >> 2, d8 = (l & 3) * 8;
#pragma unroll
        for (int it = 0; it < 4; it++) {
            bfx8 tv = *reinterpret_cast<const bfx8*>(vb + (size_t)(it * 16 + kv) * 256 + d8);
            *reinterpret_cast<bfx8*>(&Vs[(it * 16 + kv) * 32 + d8]) = tv;
        }
    }

    f32x4 s[4][4] = {};
#pragma unroll
    for (int m = 0; m < 4; m++)
#pragma unroll
        for (int n = 0; n < 4; n++)
            s[m][n] = __builtin_amdgcn_mfma_f32_16x16x32_bf16(qf[m], kf[n], s[m][n], 0, 0, 0);

    // wave-parallel softmax over 64 keys (cols = 4 n-tiles x 16 lanes)
    float rs[4][4];
#pragma unroll
    for (int m = 0; m < 4; m++)
#pragma unroll
        for (int j = 0; j < 4; j++) {
            float mx = fmaxf(fmaxf(s[m][0][j], s[m][1][j]), fmaxf(s[m][2][j], s[m][3][j]));
            mx = fmaxf(mx, __shfl_xor(mx, 1));
            mx = fmaxf(mx, __shfl_xor(mx, 2));
            mx = fmaxf(mx, __shfl_xor(mx, 4));
            mx = fmaxf(mx, __shfl_xor(mx, 8));
            float sum = 0.f;
#pragma unroll
            for (int n = 0; n < 4; n++) {
                float e = __expf(s[m][n][j] - mx);
                s[m][n][j] = e;
                sum += e;
            }
            sum += __shfl_xor(sum, 1);
            sum += __shfl_xor(sum, 2);
            sum += __shfl_xor(sum, 4);
            sum += __shfl_xor(sum, 8);
            rs[m][j] = 1.0f / sum;
        }

    // P (unnormalized, <=1) to LDS in row-major [64][pitch 80]
#pragma unroll
    for (int m = 0; m < 4; m++)
#pragma unroll
        for (int n = 0; n < 4; n++)
#pragma unroll
            for (int j = 0; j < 4; j++)
                P[(m * 16 + g * 4 + j) * 80 + n * 16 + c] = f2bf(s[m][n][j]);
    __syncthreads();

    // O = P @ V  (K = 64 keys in two 32-slices)
    f32x4 oacc[4][2] = {};
#pragma unroll
    for (int ks = 0; ks < 2; ks++) {
        bfx8 vf[2];
#pragma unroll
        for (int n2 = 0; n2 < 2; n2++)
#pragma unroll
            for (int j = 0; j < 8; j++)
                vf[n2][j] = Vs[(ks * 32 + g * 8 + j) * 32 + n2 * 16 + c];
#pragma unroll
        for (int m = 0; m < 4; m++) {
            bfx8 pf = *reinterpret_cast<const bfx8*>(&P[(m * 16 + c) * 80 + ks * 32 + g * 8]);
#pragma unroll
            for (int n2 = 0; n2 < 2; n2++)
                oacc[m][n2] = __builtin_amdgcn_mfma_f32_16x16x32_bf16(pf, vf[n2], oacc[m][n2], 0, 0, 0);
        }
    }
#pragma unroll
    for (int m = 0; m < 4; m++)
#pragma unroll
        for (int n2 = 0; n2 < 2; n2++)
#pragma unroll
            for (int j = 0; j < 4; j++)
                ob[(size_t)(m * 16 + g * 4 + j) * 256 + n2 * 16 + c] =
                    f2bf(oacc[m][n2][j] * rs[m][j]);
}

extern "C" void kernel_launch(void* const* d_in, const int* in_sizes, int n_in,
                              void* d_out, int out_size, void* d_ws, size_t ws_size,
                              hipStream_t stream) {
    const float* x   = (const float*)d_in[0];
    const float* cva = (const float*)d_in[1];
    const float* qg  = (const float*)d_in[2];
    const float* qb  = (const float*)d_in[3];
    const float* kg  = (const float*)d_in[4];
    const float* kb  = (const float*)d_in[5];
    const float* vg  = (const float*)d_in[6];
    const float* vb  = (const float*)d_in[7];
    const float* Wq  = (const float*)d_in[8];
    const float* bq  = (const float*)d_in[9];
    const float* Wk  = (const float*)d_in[10];
    const float* bk  = (const float*)d_in[11];
    const float* Wv  = (const float*)d_in[12];
    const float* bv  = (const float*)d_in[13];
    const float* Wp  = (const float*)d_in[14];
    const float* bp  = (const float*)d_in[15];
    float* out = (float*)d_out;
    char* ws = (char*)d_ws;

    const size_t SEG = (size_t)NROWS * 256 * 2;  // 16 MB bf16 [32768,256]
    short* cva_hat = (short*)(ws);
    short* xs_hat  = (short*)(ws + SEG);
    short* qkm     = (short*)(ws + 2 * SEG);   // merged q|k: [32768][512], 32 MB
    short* vm      = (short*)(ws + 4 * SEG);
    short* om      = cva_hat;  // reused after q/k GEMM consumes cva_hat
    short* wt      = (short*)(ws + 5 * SEG);
    float* bb      = (float*)(ws + 5 * SEG + 4 * 65536 * sizeof(short));
    float* bbp     = bb + 1024;

    prep_w<<<dim3(4, 16), 256, 0, stream>>>(Wq, Wk, Wv, Wp, qg, qb, kg, kb, vg, vb,
                                            wt, bbp);
    prep_b<<<4, 256, 0, stream>>>(bq, bk, bv, bp, bbp, bb);
    ln_rows<<<NROWS / 4, 256, 0, stream>>>(cva, cva_hat);
    ln_tr<<<512, 256, 0, stream>>>(x, xs_hat);

    // merged q|k GEMM: B panel = [512 rows][256], output [32768][512]
    gemm_bt<0><<<dim3(NROWS / 128, 4), 256, 0, stream>>>(cva_hat, wt, bb, qkm, 512);
    gemm_bt<0><<<dim3(NROWS / 128, 2), 256, 0, stream>>>(xs_hat, wt + 2 * 65536, bb + 512, vm, 256);

    attn<<<BATCH * 8 * 64, 64, 0, stream>>>(qkm, vm, om);

    gemm_bt<1><<<dim3(NROWS / 128, 2), 256, 0, stream>>>(om, wt + 3 * 65536, bb + 768, out, 0);
}

// Round 3
// 96.848 us; speedup vs baseline: 2.0699x; 1.1166x over previous
//
#include <hip/hip_runtime.h>
#include <hip/hip_bf16.h>

#define NTOK 4096
#define BATCH 8
#define NROWS (BATCH * NTOK)   // 32768

typedef __attribute__((ext_vector_type(8))) short bfx8;
typedef __attribute__((ext_vector_type(4))) short bfx4;
typedef __attribute__((ext_vector_type(4))) float f32x4;

__device__ __forceinline__ short f2bf(float f) {
    unsigned u = __builtin_bit_cast(unsigned, f);
    u += 0x7fffu + ((u >> 16) & 1u);
    return (short)(u >> 16);
}

#define GLDS16(gp, lp)                                                            \
    __builtin_amdgcn_global_load_lds(                                             \
        (const __attribute__((address_space(1))) void*)(gp),                      \
        (__attribute__((address_space(3))) void*)(lp), 16, 0, 0)

// ---------------- weight prep: WT[co][ci] = bf16(scale * g[ci] * W[ci][co]) ----------------
__global__ __launch_bounds__(256) void prep_w(
    const float* __restrict__ Wq, const float* __restrict__ Wk,
    const float* __restrict__ Wv, const float* __restrict__ Wp,
    const float* __restrict__ qg, const float* __restrict__ qb,
    const float* __restrict__ kg, const float* __restrict__ kb,
    const float* __restrict__ vg, const float* __restrict__ vb,
    short* __restrict__ wt, float* __restrict__ bbp) {
    int m = blockIdx.x;
    int ci0 = blockIdx.y * 16;
    const float *W, *g, *be;
    float scale = 1.0f;
    if (m == 0)      { W = Wq; g = qg; be = qb; scale = 0.17677669529663687f; }
    else if (m == 1) { W = Wk; g = kg; be = kb; }
    else if (m == 2) { W = Wv; g = vg; be = vb; }
    else             { W = Wp; g = nullptr; be = nullptr; }
    __shared__ float tile[16][257];
    int t = threadIdx.x;
#pragma unroll
    for (int i = 0; i < 16; i++)
        tile[i][t] = W[(size_t)(ci0 + i) * 256 + t];
    __syncthreads();
    float p = 0.f;
    if (be) {
#pragma unroll
        for (int i = 0; i < 16; i++) p += be[ci0 + i] * tile[i][t];
    }
    bbp[(m * 16 + blockIdx.y) * 256 + t] = p;
    short* WT = wt + m * 65536 + t * 256 + ci0;
    bfx8 o0, o1;
#pragma unroll
    for (int j = 0; j < 8; j++) {
        float gv = g ? g[ci0 + j] : 1.0f;
        o0[j] = f2bf(scale * gv * tile[j][t]);
    }
#pragma unroll
    for (int j = 0; j < 8; j++) {
        float gv = g ? g[ci0 + 8 + j] : 1.0f;
        o1[j] = f2bf(scale * gv * tile[8 + j][t]);
    }
    *reinterpret_cast<bfx8*>(WT) = o0;
    *reinterpret_cast<bfx8*>(WT + 8) = o1;
}

__global__ __launch_bounds__(256) void prep_b(
    const float* __restrict__ bq, const float* __restrict__ bk,
    const float* __restrict__ bv, const float* __restrict__ bp,
    const float* __restrict__ bbp, float* __restrict__ bb) {
    int m = blockIdx.x, t = threadIdx.x;
    const float* bias = (m == 0) ? bq : (m == 1) ? bk : (m == 2) ? bv : bp;
    float scale = (m == 0) ? 0.17677669529663687f : 1.0f;
    float s = bias[t];
#pragma unroll
    for (int i = 0; i < 16; i++) s += bbp[(m * 16 + i) * 256 + t];
    bb[m * 256 + t] = scale * s;
}

// ---------------- LN over contiguous rows (cva) ----------------
__global__ __launch_bounds__(256) void ln_rows(const float* __restrict__ src,
                                               short* __restrict__ dst) {
    int row = blockIdx.x * 4 + (threadIdx.x >> 6);
    int lane = threadIdx.x & 63;
    const float4 v = *reinterpret_cast<const float4*>(src + (size_t)row * 256 + lane * 4);
    float s = v.x + v.y + v.z + v.w;
    float q = v.x * v.x + v.y * v.y + v.z * v.z + v.w * v.w;
#pragma unroll
    for (int m = 1; m < 64; m <<= 1) { s += __shfl_xor(s, m); q += __shfl_xor(q, m); }
    float mean = s * (1.0f / 256.0f);
    float var  = q * (1.0f / 256.0f) - mean * mean;
    float rstd = rsqrtf(var + 1e-5f);
    bfx4 o;
    o[0] = f2bf((v.x - mean) * rstd);
    o[1] = f2bf((v.y - mean) * rstd);
    o[2] = f2bf((v.z - mean) * rstd);
    o[3] = f2bf((v.w - mean) * rstd);
    *reinterpret_cast<bfx4*>(dst + (size_t)row * 256 + lane * 4) = o;
}

// ---------------- LN over transposed view xs[b,n,c] = x[b,c,n] ----------------
__global__ __launch_bounds__(256) void ln_tr(const float* __restrict__ x,
                                             short* __restrict__ dst) {
    int b = blockIdx.x >> 6;
    int n0 = (blockIdx.x & 63) * 64;
    __shared__ float tile[256][65];
    int t = threadIdx.x;
    int nl = t & 63, cq = t >> 6;
    const float* xb = x + (size_t)b * 256 * 4096 + n0;
    for (int c0 = 0; c0 < 256; c0 += 4)
        tile[c0 + cq][nl] = xb[(size_t)(c0 + cq) * 4096 + nl];
    __syncthreads();
    int n = t >> 2, j = t & 3;
    float s = 0.f, q = 0.f;
    for (int c = j; c < 256; c += 4) { float v = tile[c][n]; s += v; q += v * v; }
    s += __shfl_xor(s, 1); s += __shfl_xor(s, 2);
    q += __shfl_xor(q, 1); q += __shfl_xor(q, 2);
    float mean = s * (1.0f / 256.0f);
    float var  = q * (1.0f / 256.0f) - mean * mean;
    float rstd = rsqrtf(var + 1e-5f);
    short* drow = dst + (size_t)(b * 4096 + n0 + n) * 256;
    for (int c0 = j * 64; c0 < (j + 1) * 64; c0 += 8) {
        bfx8 o;
#pragma unroll
        for (int jj = 0; jj < 8; jj++) o[jj] = f2bf((tile[c0 + jj][n] - mean) * rstd);
        *reinterpret_cast<bfx8*>(drow + c0) = o;
    }
}

// ---------------- fused q|k|v GEMM, XCD-aware flat grid (1536 blocks) ----------------
// panel 0..3: qk (A=cva_hat, out stride 512); panel 4..5: v (A=xs_hat, out stride 256)
__global__ __launch_bounds__(256) void gemm_qkv(const short* __restrict__ cva_hat,
                                                const short* __restrict__ xs_hat,
                                                const short* __restrict__ wt,
                                                const float* __restrict__ bb,
                                                short* __restrict__ qkm,
                                                short* __restrict__ vm) {
    __shared__ short As[128 * 64];
    __shared__ short Bs[128 * 64];
    int flat = blockIdx.x;
    int xcd = flat & 7, idx = flat >> 3;      // each XCD: 32 row-tiles x 6 panels
    int rowtile = xcd * 32 + (idx & 31);
    int panel = idx >> 5;
    const short* A; const short* Bw; short* out; int ostride, col0; const float* bias;
    if (panel < 4) { A = cva_hat; Bw = wt;            out = qkm; ostride = 512; col0 = panel * 128;      bias = bb; }
    else           { A = xs_hat;  Bw = wt + 2 * 65536; out = vm;  ostride = 256; col0 = (panel - 4) * 128; bias = bb + 512; }
    int t = threadIdx.x;
    int w = t >> 6, l = t & 63;
    int c = l & 15, g = l >> 4;
    int row0 = rowtile * 128;
    int wr = w >> 1, wc = w & 1;
    f32x4 acc[4][4] = {};
    const short* Ag = A + (size_t)row0 * 256;
    const short* Bg = Bw + (size_t)col0 * 256;
    int srow = w * 8 + (l >> 3);
    int sk = (l & 7) * 8;
    for (int kt = 0; kt < 4; kt++) {
        __syncthreads();
#pragma unroll
        for (int i = 0; i < 4; i++)
            GLDS16(Ag + (size_t)(i * 32 + srow) * 256 + kt * 64 + sk, As + i * 2048 + w * 512);
#pragma unroll
        for (int i = 0; i < 4; i++)
            GLDS16(Bg + (size_t)(i * 32 + srow) * 256 + kt * 64 + sk, Bs + i * 2048 + w * 512);
        __syncthreads();
#pragma unroll
        for (int ks = 0; ks < 2; ks++) {
            bfx8 af[4], bf[4];
#pragma unroll
            for (int m = 0; m < 4; m++)
                af[m] = *reinterpret_cast<const bfx8*>(As + (wr * 64 + m * 16 + c) * 64 + ks * 32 + g * 8);
#pragma unroll
            for (int n = 0; n < 4; n++)
                bf[n] = *reinterpret_cast<const bfx8*>(Bs + (wc * 64 + n * 16 + c) * 64 + ks * 32 + g * 8);
#pragma unroll
            for (int m = 0; m < 4; m++)
#pragma unroll
                for (int n = 0; n < 4; n++)
                    acc[m][n] = __builtin_amdgcn_mfma_f32_16x16x32_bf16(af[m], bf[n], acc[m][n], 0, 0, 0);
        }
    }
#pragma unroll
    for (int m = 0; m < 4; m++)
#pragma unroll
        for (int n = 0; n < 4; n++)
#pragma unroll
            for (int j = 0; j < 4; j++) {
                int r = row0 + wr * 64 + m * 16 + g * 4 + j;
                int col = col0 + wc * 64 + n * 16 + c;
                out[(size_t)r * ostride + col] = f2bf(acc[m][n][j] + bias[col]);
            }
}

// ---------------- fused block-local attention + output projection ----------------
// 512 blocks (b, chunk) x 512 threads (8 waves, one head each).
__global__ __launch_bounds__(512) void attn_proj(const short* __restrict__ qk,
                                                 const short* __restrict__ v,
                                                 const short* __restrict__ wp,
                                                 const float* __restrict__ bias,
                                                 float* __restrict__ out) {
    int id = blockIdx.x;
    int b = id >> 6, ch = id & 63;
    int r0 = b * 4096 + ch * 64;
    int t = threadIdx.x;
    int w = t >> 6, l = t & 63, c = l & 15, g = l >> 4;
    int h = w;

    const int O_PITCH = 264;   // 2-way bank alias on b128 reads = free
    const int P_PITCH = 72;
    __shared__ short o_s[64 * 264];            // 33.8 KB
    __shared__ short pw[8][64 * 72 + 64 * 32]; // per-wave P + Vs, 13312 B each
    short* P  = pw[w];
    short* Vs = pw[w] + 64 * 72;

    const short* qb = qk + (size_t)r0 * 512 + h * 32;
    const short* kb = qb + 256;
    const short* vb = v + (size_t)r0 * 256 + h * 32;

    bfx8 qf[4], kf[4];
#pragma unroll
    for (int m = 0; m < 4; m++)
        qf[m] = *reinterpret_cast<const bfx8*>(qb + (size_t)(m * 16 + c) * 512 + g * 8);
#pragma unroll
    for (int n = 0; n < 4; n++)
        kf[n] = *reinterpret_cast<const bfx8*>(kb + (size_t)(n * 16 + c) * 512 + g * 8);

    // stage this head's V tile [64 kv][32 d]
    {
        int kv = l >> 2, d8 = (l & 3) * 8;
#pragma unroll
        for (int it = 0; it < 4; it++) {
            bfx8 tv = *reinterpret_cast<const bfx8*>(vb + (size_t)(it * 16 + kv) * 256 + d8);
            *reinterpret_cast<bfx8*>(&Vs[(it * 16 + kv) * 32 + d8]) = tv;
        }
    }

    f32x4 s[4][4] = {};
#pragma unroll
    for (int m = 0; m < 4; m++)
#pragma unroll
        for (int n = 0; n < 4; n++)
            s[m][n] = __builtin_amdgcn_mfma_f32_16x16x32_bf16(qf[m], kf[n], s[m][n], 0, 0, 0);

    float rs[4][4];
#pragma unroll
    for (int m = 0; m < 4; m++)
#pragma unroll
        for (int j = 0; j < 4; j++) {
            float mx = fmaxf(fmaxf(s[m][0][j], s[m][1][j]), fmaxf(s[m][2][j], s[m][3][j]));
            mx = fmaxf(mx, __shfl_xor(mx, 1));
            mx = fmaxf(mx, __shfl_xor(mx, 2));
            mx = fmaxf(mx, __shfl_xor(mx, 4));
            mx = fmaxf(mx, __shfl_xor(mx, 8));
            float sum = 0.f;
#pragma unroll
            for (int n = 0; n < 4; n++) {
                float e = __expf(s[m][n][j] - mx);
                s[m][n][j] = e;
                sum += e;
            }
            sum += __shfl_xor(sum, 1);
            sum += __shfl_xor(sum, 2);
            sum += __shfl_xor(sum, 4);
            sum += __shfl_xor(sum, 8);
            rs[m][j] = 1.0f / sum;
        }

#pragma unroll
    for (int m = 0; m < 4; m++)
#pragma unroll
        for (int n = 0; n < 4; n++)
#pragma unroll
            for (int j = 0; j < 4; j++)
                P[(m * 16 + g * 4 + j) * P_PITCH + n * 16 + c] = f2bf(s[m][n][j]);
    __builtin_amdgcn_s_waitcnt(0);

    // O_head = P @ V -> o_s[token][h*32 + d]
    f32x4 oacc[4][2] = {};
#pragma unroll
    for (int ks = 0; ks < 2; ks++) {
        bfx8 vf[2];
#pragma unroll
        for (int n2 = 0; n2 < 2; n2++)
#pragma unroll
            for (int j = 0; j < 8; j++)
                vf[n2][j] = Vs[(ks * 32 + g * 8 + j) * 32 + n2 * 16 + c];
#pragma unroll
        for (int m = 0; m < 4; m++) {
            bfx8 pf = *reinterpret_cast<const bfx8*>(&P[(m * 16 + c) * P_PITCH + ks * 32 + g * 8]);
#pragma unroll
            for (int n2 = 0; n2 < 2; n2++)
                oacc[m][n2] = __builtin_amdgcn_mfma_f32_16x16x32_bf16(pf, vf[n2], oacc[m][n2], 0, 0, 0);
        }
    }
#pragma unroll
    for (int m = 0; m < 4; m++)
#pragma unroll
        for (int n2 = 0; n2 < 2; n2++)
#pragma unroll
            for (int j = 0; j < 4; j++)
                o_s[(m * 16 + g * 4 + j) * O_PITCH + h * 32 + n2 * 16 + c] =
                    f2bf(oacc[m][n2][j] * rs[m][j]);
    __syncthreads();

    // projection: wave w computes channels [32w, 32w+32) for all 64 tokens
    f32x4 pacc[4][2] = {};
    const short* wpb = wp + (size_t)(w * 32) * 256;
#pragma unroll
    for (int ks = 0; ks < 8; ks++) {
        bfx8 af[4], bfr[2];
#pragma unroll
        for (int m = 0; m < 4; m++)
            af[m] = *reinterpret_cast<const bfx8*>(&o_s[(m * 16 + c) * O_PITCH + ks * 32 + g * 8]);
#pragma unroll
        for (int n = 0; n < 2; n++)
            bfr[n] = *reinterpret_cast<const bfx8*>(wpb + (size_t)(n * 16 + c) * 256 + ks * 32 + g * 8);
#pragma unroll
        for (int m = 0; m < 4; m++)
#pragma unroll
            for (int n = 0; n < 2; n++)
                pacc[m][n] = __builtin_amdgcn_mfma_f32_16x16x32_bf16(af[m], bfr[n], pacc[m][n], 0, 0, 0);
    }

    // transposed fp32 epilogue: out[b, co, ch*64 + token]
    float* trw = reinterpret_cast<float*>(pw[w]);   // P/Vs dead; 16x65 floats fit
    float* outb = out + (size_t)b * 1048576 + ch * 64;
#pragma unroll
    for (int p = 0; p < 2; p++) {
        float bv = bias[w * 32 + p * 16 + c];
#pragma unroll
        for (int m = 0; m < 4; m++)
#pragma unroll
            for (int j = 0; j < 4; j++)
                trw[c * 65 + m * 16 + g * 4 + j] = pacc[m][p][j] + bv;
        __builtin_amdgcn_s_waitcnt(0);
#pragma unroll
        for (int cl = 0; cl < 16; cl++) {
            int co = w * 32 + p * 16 + cl;
            outb[(size_t)co * 4096 + l] = trw[cl * 65 + l];
        }
        __builtin_amdgcn_s_waitcnt(0);
    }
}

extern "C" void kernel_launch(void* const* d_in, const int* in_sizes, int n_in,
                              void* d_out, int out_size, void* d_ws, size_t ws_size,
                              hipStream_t stream) {
    const float* x   = (const float*)d_in[0];
    const float* cva = (const float*)d_in[1];
    const float* qg  = (const float*)d_in[2];
    const float* qb  = (const float*)d_in[3];
    const float* kg  = (const float*)d_in[4];
    const float* kb  = (const float*)d_in[5];
    const float* vg  = (const float*)d_in[6];
    const float* vb  = (const float*)d_in[7];
    const float* Wq  = (const float*)d_in[8];
    const float* bq  = (const float*)d_in[9];
    const float* Wk  = (const float*)d_in[10];
    const float* bk  = (const float*)d_in[11];
    const float* Wv  = (const float*)d_in[12];
    const float* bv  = (const float*)d_in[13];
    const float* Wp  = (const float*)d_in[14];
    const float* bp  = (const float*)d_in[15];
    float* out = (float*)d_out;
    char* ws = (char*)d_ws;

    const size_t SEG = (size_t)NROWS * 256 * 2;  // 16 MB bf16 [32768,256]
    short* cva_hat = (short*)(ws);
    short* xs_hat  = (short*)(ws + SEG);
    short* qkm     = (short*)(ws + 2 * SEG);   // merged q|k: [32768][512], 32 MB
    short* vm      = (short*)(ws + 4 * SEG);
    short* wt      = (short*)(ws + 5 * SEG);
    float* bb      = (float*)(ws + 5 * SEG + 4 * 65536 * sizeof(short));
    float* bbp     = bb + 1024;

    prep_w<<<dim3(4, 16), 256, 0, stream>>>(Wq, Wk, Wv, Wp, qg, qb, kg, kb, vg, vb,
                                            wt, bbp);
    prep_b<<<4, 256, 0, stream>>>(bq, bk, bv, bp, bbp, bb);
    ln_rows<<<NROWS / 4, 256, 0, stream>>>(cva, cva_hat);
    ln_tr<<<512, 256, 0, stream>>>(x, xs_hat);

    gemm_qkv<<<1536, 256, 0, stream>>>(cva_hat, xs_hat, wt, bb, qkm, vm);

    attn_proj<<<512, 512, 0, stream>>>(qkm, vm, wt + 3 * 65536, bb + 768, out);
}

// Round 4
// 79.368 us; speedup vs baseline: 2.5258x; 1.2202x over previous
//
#include <hip/hip_runtime.h>
#include <hip/hip_bf16.h>

#define NTOK 4096
#define BATCH 8
#define NROWS (BATCH * NTOK)   // 32768

typedef __attribute__((ext_vector_type(8))) short bfx8;
typedef __attribute__((ext_vector_type(4))) short bfx4;
typedef __attribute__((ext_vector_type(4))) float f32x4;

__device__ __forceinline__ short f2bf(float f) {
    unsigned u = __builtin_bit_cast(unsigned, f);
    u += 0x7fffu + ((u >> 16) & 1u);
    return (short)(u >> 16);
}

#define MFMA16(a, b, c) __builtin_amdgcn_mfma_f32_16x16x32_bf16(a, b, c, 0, 0, 0)

// ---------------- weight prep: WT[co][ci] = bf16(scale * g[ci] * W[ci][co]) ----------------
__global__ __launch_bounds__(256) void prep_w(
    const float* __restrict__ Wq, const float* __restrict__ Wk,
    const float* __restrict__ Wv, const float* __restrict__ Wp,
    const float* __restrict__ qg, const float* __restrict__ qb,
    const float* __restrict__ kg, const float* __restrict__ kb,
    const float* __restrict__ vg, const float* __restrict__ vb,
    short* __restrict__ wt, float* __restrict__ bbp) {
    int m = blockIdx.x;
    int ci0 = blockIdx.y * 16;
    const float *W, *g, *be;
    float scale = 1.0f;
    if (m == 0)      { W = Wq; g = qg; be = qb; scale = 0.17677669529663687f; }
    else if (m == 1) { W = Wk; g = kg; be = kb; }
    else if (m == 2) { W = Wv; g = vg; be = vb; }
    else             { W = Wp; g = nullptr; be = nullptr; }
    __shared__ float tile[16][257];
    int t = threadIdx.x;
#pragma unroll
    for (int i = 0; i < 16; i++)
        tile[i][t] = W[(size_t)(ci0 + i) * 256 + t];
    __syncthreads();
    float p = 0.f;
    if (be) {
#pragma unroll
        for (int i = 0; i < 16; i++) p += be[ci0 + i] * tile[i][t];
    }
    bbp[(m * 16 + blockIdx.y) * 256 + t] = p;
    short* WT = wt + m * 65536 + t * 256 + ci0;
    bfx8 o0, o1;
#pragma unroll
    for (int j = 0; j < 8; j++) {
        float gv = g ? g[ci0 + j] : 1.0f;
        o0[j] = f2bf(scale * gv * tile[j][t]);
    }
#pragma unroll
    for (int j = 0; j < 8; j++) {
        float gv = g ? g[ci0 + 8 + j] : 1.0f;
        o1[j] = f2bf(scale * gv * tile[8 + j][t]);
    }
    *reinterpret_cast<bfx8*>(WT) = o0;
    *reinterpret_cast<bfx8*>(WT + 8) = o1;
}

__global__ __launch_bounds__(256) void prep_b(
    const float* __restrict__ bq, const float* __restrict__ bk,
    const float* __restrict__ bv, const float* __restrict__ bp,
    const float* __restrict__ bbp, float* __restrict__ bb) {
    int m = blockIdx.x, t = threadIdx.x;
    const float* bias = (m == 0) ? bq : (m == 1) ? bk : (m == 2) ? bv : bp;
    float scale = (m == 0) ? 0.17677669529663687f : 1.0f;
    float s = bias[t];
#pragma unroll
    for (int i = 0; i < 16; i++) s += bbp[(m * 16 + i) * 256 + t];
    bb[m * 256 + t] = scale * s;
}

// ---------------- mega kernel: LN + qkv GEMM + attention + projection ----------------
// 512 blocks (b, chunk) x 512 threads (8 waves; wave = head = 32-col strip).
// LDS slots (pitch 264 shorts = 2-way-free banks):
//   A: cva_hat -> xs_hat -> o_s      B: q -> P(lo)      C: k -> P(hi)      D: v
__global__ __launch_bounds__(512) void mega(const float* __restrict__ x,
                                            const float* __restrict__ cva,
                                            const short* __restrict__ wt,
                                            const float* __restrict__ bb,
                                            float* __restrict__ out) {
    int id = blockIdx.x;
    int b = id >> 6, ch = id & 63;
    int t = threadIdx.x, w = t >> 6, l = t & 63, c = l & 15, g = l >> 4;
    int h = w;

    __shared__ short lds[4 * 64 * 264];   // 135168 B
    __shared__ float red[8][64][2];       // 4096 B
    short* A    = lds;
    short* B    = lds + 16896;
    short* Cs   = lds + 2 * 16896;
    short* D    = lds + 3 * 16896;
    short* Preg = B;                      // P region overlays B|C (64 KB)

    const float* xb   = x + (size_t)b * 1048576 + ch * 64;
    const float* cvab = cva + (size_t)(b * 4096 + ch * 64) * 256;

    // issue x loads early (held in regs through ph2)
    float xg[32];
#pragma unroll
    for (int i = 0; i < 32; i++) xg[i] = xb[(size_t)(w * 32 + i) * 4096 + l];

    // ph1: LN over cva rows -> A (each wave 8 rows)
#pragma unroll
    for (int i = 0; i < 8; i++) {
        int row = w * 8 + i;
        float4 v = *reinterpret_cast<const float4*>(cvab + (size_t)row * 256 + l * 4);
        float s = v.x + v.y + v.z + v.w;
        float q2 = v.x * v.x + v.y * v.y + v.z * v.z + v.w * v.w;
#pragma unroll
        for (int m = 1; m < 64; m <<= 1) { s += __shfl_xor(s, m); q2 += __shfl_xor(q2, m); }
        float mean = s * (1.0f / 256.0f);
        float var  = q2 * (1.0f / 256.0f) - mean * mean;
        float rstd = rsqrtf(var + 1e-5f);
        bfx4 o;
        o[0] = f2bf((v.x - mean) * rstd);
        o[1] = f2bf((v.y - mean) * rstd);
        o[2] = f2bf((v.z - mean) * rstd);
        o[3] = f2bf((v.w - mean) * rstd);
        *reinterpret_cast<bfx4*>(A + row * 264 + l * 4) = o;
    }

    // x stats partials (token = l, c-slice = w*32..w*32+32)
    {
        float s = 0.f, q2 = 0.f;
#pragma unroll
        for (int i = 0; i < 32; i++) { s += xg[i]; q2 += xg[i] * xg[i]; }
        red[w][l][0] = s;
        red[w][l][1] = q2;
    }
    __syncthreads();  // bar0: A ready, red ready

    float xmean, xrstd;
    {
        float s = 0.f, q2 = 0.f;
#pragma unroll
        for (int j2 = 0; j2 < 8; j2++) { s += red[j2][l][0]; q2 += red[j2][l][1]; }
        xmean = s * (1.0f / 256.0f);
        xrstd = rsqrtf(q2 * (1.0f / 256.0f) - xmean * xmean + 1e-5f);
    }

    // ph2: q,k GEMM from A (cva_hat); weights streamed from global (L2)
    {
        f32x4 qacc[4][2] = {}, kacc[4][2] = {};
        const short* wq0 = wt + (size_t)(w * 32 + c) * 256 + g * 8;
        const short* wq1 = wq0 + 16 * 256;
        const short* wk0 = wq0 + 65536;
        const short* wk1 = wq1 + 65536;
#pragma unroll
        for (int ks = 0; ks < 8; ks++) {
            bfx8 af[4];
#pragma unroll
            for (int m = 0; m < 4; m++)
                af[m] = *reinterpret_cast<const bfx8*>(A + (m * 16 + c) * 264 + ks * 32 + g * 8);
            bfx8 q0 = *reinterpret_cast<const bfx8*>(wq0 + ks * 32);
            bfx8 q1 = *reinterpret_cast<const bfx8*>(wq1 + ks * 32);
            bfx8 k0 = *reinterpret_cast<const bfx8*>(wk0 + ks * 32);
            bfx8 k1 = *reinterpret_cast<const bfx8*>(wk1 + ks * 32);
#pragma unroll
            for (int m = 0; m < 4; m++) {
                qacc[m][0] = MFMA16(af[m], q0, qacc[m][0]);
                qacc[m][1] = MFMA16(af[m], q1, qacc[m][1]);
                kacc[m][0] = MFMA16(af[m], k0, kacc[m][0]);
                kacc[m][1] = MFMA16(af[m], k1, kacc[m][1]);
            }
        }
        float bq0 = bb[w * 32 + c], bq1 = bb[w * 32 + 16 + c];
        float bk0 = bb[256 + w * 32 + c], bk1 = bb[256 + w * 32 + 16 + c];
#pragma unroll
        for (int m = 0; m < 4; m++)
#pragma unroll
            for (int j = 0; j < 4; j++) {
                int row = m * 16 + g * 4 + j;
                B [row * 264 + w * 32 + c]      = f2bf(qacc[m][0][j] + bq0);
                B [row * 264 + w * 32 + 16 + c] = f2bf(qacc[m][1][j] + bq1);
                Cs[row * 264 + w * 32 + c]      = f2bf(kacc[m][0][j] + bk0);
                Cs[row * 264 + w * 32 + 16 + c] = f2bf(kacc[m][1][j] + bk1);
            }
    }
    __syncthreads();  // bar1: all A reads (ph2) done

    // ph3: normalize held x -> A (xs_hat), row = token l, cols w*32..+32
#pragma unroll
    for (int i2 = 0; i2 < 4; i2++) {
        bfx8 o;
#pragma unroll
        for (int jj = 0; jj < 8; jj++) o[jj] = f2bf((xg[i2 * 8 + jj] - xmean) * xrstd);
        *reinterpret_cast<bfx8*>(A + l * 264 + w * 32 + i2 * 8) = o;
    }
    __syncthreads();  // bar2: xs_hat ready

    // ph4: v GEMM from A (xs_hat) -> D
    {
        f32x4 vacc[4][2] = {};
        const short* wv0 = wt + 2 * 65536 + (size_t)(w * 32 + c) * 256 + g * 8;
        const short* wv1 = wv0 + 16 * 256;
#pragma unroll
        for (int ks = 0; ks < 8; ks++) {
            bfx8 af[4];
#pragma unroll
            for (int m = 0; m < 4; m++)
                af[m] = *reinterpret_cast<const bfx8*>(A + (m * 16 + c) * 264 + ks * 32 + g * 8);
            bfx8 v0 = *reinterpret_cast<const bfx8*>(wv0 + ks * 32);
            bfx8 v1 = *reinterpret_cast<const bfx8*>(wv1 + ks * 32);
#pragma unroll
            for (int m = 0; m < 4; m++) {
                vacc[m][0] = MFMA16(af[m], v0, vacc[m][0]);
                vacc[m][1] = MFMA16(af[m], v1, vacc[m][1]);
            }
        }
        float bv0 = bb[512 + w * 32 + c], bv1 = bb[512 + w * 32 + 16 + c];
#pragma unroll
        for (int m = 0; m < 4; m++)
#pragma unroll
            for (int j = 0; j < 4; j++) {
                int row = m * 16 + g * 4 + j;
                D[row * 264 + w * 32 + c]      = f2bf(vacc[m][0][j] + bv0);
                D[row * 264 + w * 32 + 16 + c] = f2bf(vacc[m][1][j] + bv1);
            }
    }

    // ph5: QK^T for own head (B,C are own-wave data) + softmax
    f32x4 s[4][4] = {};
    {
        bfx8 qf[4], kf[4];
#pragma unroll
        for (int m = 0; m < 4; m++)
            qf[m] = *reinterpret_cast<const bfx8*>(B + (m * 16 + c) * 264 + h * 32 + g * 8);
#pragma unroll
        for (int n = 0; n < 4; n++)
            kf[n] = *reinterpret_cast<const bfx8*>(Cs + (n * 16 + c) * 264 + h * 32 + g * 8);
#pragma unroll
        for (int m = 0; m < 4; m++)
#pragma unroll
            for (int n = 0; n < 4; n++)
                s[m][n] = MFMA16(qf[m], kf[n], s[m][n]);
    }
    float rs[4][4];
#pragma unroll
    for (int m = 0; m < 4; m++)
#pragma unroll
        for (int j = 0; j < 4; j++) {
            float mx = fmaxf(fmaxf(s[m][0][j], s[m][1][j]), fmaxf(s[m][2][j], s[m][3][j]));
            mx = fmaxf(mx, __shfl_xor(mx, 1));
            mx = fmaxf(mx, __shfl_xor(mx, 2));
            mx = fmaxf(mx, __shfl_xor(mx, 4));
            mx = fmaxf(mx, __shfl_xor(mx, 8));
            float sum = 0.f;
#pragma unroll
            for (int n = 0; n < 4; n++) {
                float e = __expf(s[m][n][j] - mx);
                s[m][n][j] = e;
                sum += e;
            }
            sum += __shfl_xor(sum, 1);
            sum += __shfl_xor(sum, 2);
            sum += __shfl_xor(sum, 4);
            sum += __shfl_xor(sum, 8);
            rs[m][j] = 1.0f / sum;
        }
    __syncthreads();  // bar3: all B/C reads + all A reads (ph4) done

    // P (bf16, XOR-swizzled [64][64] per head) -> PV -> o_s (A)
    {
        short* Phs = Preg + h * 4096;
        const char* Phc = (const char*)Phs;
#pragma unroll
        for (int m = 0; m < 4; m++)
#pragma unroll
            for (int n = 0; n < 4; n++)
#pragma unroll
                for (int j = 0; j < 4; j++) {
                    int row = m * 16 + g * 4 + j;
                    int sw = (row & 7) << 4;
                    Phs[row * 64 + ((((n * 16 + c) << 1) ^ sw) >> 1)] = f2bf(s[m][n][j]);
                }
        __builtin_amdgcn_s_waitcnt(0);

        f32x4 oacc[4][2] = {};
#pragma unroll
        for (int ks = 0; ks < 2; ks++) {
            bfx8 vf[2];
#pragma unroll
            for (int n2 = 0; n2 < 2; n2++)
#pragma unroll
                for (int jj = 0; jj < 8; jj++)
                    vf[n2][jj] = D[(ks * 32 + g * 8 + jj) * 264 + h * 32 + n2 * 16 + c];
#pragma unroll
            for (int m = 0; m < 4; m++) {
                int row = m * 16 + c;
                int sw = (row & 7) << 4;
                bfx8 pf = *reinterpret_cast<const bfx8*>(Phc + row * 128 + ((ks * 64 + g * 16) ^ sw));
#pragma unroll
                for (int n2 = 0; n2 < 2; n2++)
                    oacc[m][n2] = MFMA16(pf, vf[n2], oacc[m][n2]);
            }
        }
#pragma unroll
        for (int m = 0; m < 4; m++)
#pragma unroll
            for (int n2 = 0; n2 < 2; n2++)
#pragma unroll
                for (int j = 0; j < 4; j++)
                    A[(m * 16 + g * 4 + j) * 264 + h * 32 + n2 * 16 + c] =
                        f2bf(oacc[m][n2][j] * rs[m][j]);
    }
    __syncthreads();  // bar4: o_s ready

    // ph6: projection (wave = 32 output channels) + transposed fp32 store
    {
        f32x4 pacc[4][2] = {};
        const short* wp0 = wt + 3 * 65536 + (size_t)(w * 32 + c) * 256 + g * 8;
        const short* wp1 = wp0 + 16 * 256;
#pragma unroll
        for (int ks = 0; ks < 8; ks++) {
            bfx8 af[4];
#pragma unroll
            for (int m = 0; m < 4; m++)
                af[m] = *reinterpret_cast<const bfx8*>(A + (m * 16 + c) * 264 + ks * 32 + g * 8);
            bfx8 p0 = *reinterpret_cast<const bfx8*>(wp0 + ks * 32);
            bfx8 p1 = *reinterpret_cast<const bfx8*>(wp1 + ks * 32);
#pragma unroll
            for (int m = 0; m < 4; m++) {
                pacc[m][0] = MFMA16(af[m], p0, pacc[m][0]);
                pacc[m][1] = MFMA16(af[m], p1, pacc[m][1]);
            }
        }
        float* trw = reinterpret_cast<float*>(Preg + h * 4096);  // own P slot, dead
        float* outb = out + (size_t)b * 1048576 + ch * 64;
#pragma unroll
        for (int p = 0; p < 2; p++) {
            float bv = bb[768 + w * 32 + p * 16 + c];
#pragma unroll
            for (int m = 0; m < 4; m++)
#pragma unroll
                for (int j = 0; j < 4; j++)
                    trw[c * 65 + m * 16 + g * 4 + j] = pacc[m][p][j] + bv;
            __builtin_amdgcn_s_waitcnt(0);
#pragma unroll
            for (int cl = 0; cl < 16; cl++) {
                int co = w * 32 + p * 16 + cl;
                outb[(size_t)co * 4096 + l] = trw[cl * 65 + l];
            }
            __builtin_amdgcn_s_waitcnt(0);
        }
    }
}

extern "C" void kernel_launch(void* const* d_in, const int* in_sizes, int n_in,
                              void* d_out, int out_size, void* d_ws, size_t ws_size,
                              hipStream_t stream) {
    const float* x   = (const float*)d_in[0];
    const float* cva = (const float*)d_in[1];
    const float* qg  = (const float*)d_in[2];
    const float* qb  = (const float*)d_in[3];
    const float* kg  = (const float*)d_in[4];
    const float* kb  = (const float*)d_in[5];
    const float* vg  = (const float*)d_in[6];
    const float* vb  = (const float*)d_in[7];
    const float* Wq  = (const float*)d_in[8];
    const float* bq  = (const float*)d_in[9];
    const float* Wk  = (const float*)d_in[10];
    const float* bk  = (const float*)d_in[11];
    const float* Wv  = (const float*)d_in[12];
    const float* bv  = (const float*)d_in[13];
    const float* Wp  = (const float*)d_in[14];
    const float* bp  = (const float*)d_in[15];
    float* out = (float*)d_out;
    char* ws = (char*)d_ws;

    short* wt  = (short*)(ws);
    float* bb  = (float*)(ws + 4 * 65536 * sizeof(short));
    float* bbp = bb + 1024;

    prep_w<<<dim3(4, 16), 256, 0, stream>>>(Wq, Wk, Wv, Wp, qg, qb, kg, kb, vg, vb,
                                            wt, bbp);
    prep_b<<<4, 256, 0, stream>>>(bq, bk, bv, bp, bbp, bb);

    mega<<<512, 512, 0, stream>>>(x, cva, wt, bb, out);
}

// Round 5
// 67.758 us; speedup vs baseline: 2.9586x; 1.1713x over previous
//
#include <hip/hip_runtime.h>
#include <hip/hip_bf16.h>

#define NTOK 4096
#define BATCH 8
#define NROWS (BATCH * NTOK)   // 32768

typedef __attribute__((ext_vector_type(8))) short bfx8;
typedef __attribute__((ext_vector_type(4))) short bfx4;
typedef __attribute__((ext_vector_type(4))) float f32x4;

__device__ __forceinline__ short f2bf(float f) {
    unsigned u = __builtin_bit_cast(unsigned, f);
    u += 0x7fffu + ((u >> 16) & 1u);
    return (short)(u >> 16);
}
__device__ __forceinline__ unsigned pk2(float a, float b) {
    return (unsigned)(unsigned short)f2bf(a) | ((unsigned)(unsigned short)f2bf(b) << 16);
}

#define MFMA16(a, b, c) __builtin_amdgcn_mfma_f32_16x16x32_bf16(a, b, c, 0, 0, 0)
#define LGKM0()                                              \
    do {                                                     \
        asm volatile("s_waitcnt lgkmcnt(0)" ::: "memory");   \
        __builtin_amdgcn_sched_barrier(0);                   \
    } while (0)

// ---------------- weight prep: WT[co][ci] = bf16(scale * g[ci] * W[ci][co]) ----------------
__global__ __launch_bounds__(256) void prep_w(
    const float* __restrict__ Wq, const float* __restrict__ Wk,
    const float* __restrict__ Wv, const float* __restrict__ Wp,
    const float* __restrict__ qg, const float* __restrict__ qb,
    const float* __restrict__ kg, const float* __restrict__ kb,
    const float* __restrict__ vg, const float* __restrict__ vb,
    short* __restrict__ wt, float* __restrict__ bbp) {
    int m = blockIdx.x;
    int ci0 = blockIdx.y * 16;
    const float *W, *g, *be;
    float scale = 1.0f;
    if (m == 0)      { W = Wq; g = qg; be = qb; scale = 0.17677669529663687f; }
    else if (m == 1) { W = Wk; g = kg; be = kb; }
    else if (m == 2) { W = Wv; g = vg; be = vb; }
    else             { W = Wp; g = nullptr; be = nullptr; }
    __shared__ float tile[16][257];
    int t = threadIdx.x;
#pragma unroll
    for (int i = 0; i < 16; i++)
        tile[i][t] = W[(size_t)(ci0 + i) * 256 + t];
    __syncthreads();
    float p = 0.f;
    if (be) {
#pragma unroll
        for (int i = 0; i < 16; i++) p += be[ci0 + i] * tile[i][t];
    }
    bbp[(m * 16 + blockIdx.y) * 256 + t] = p;
    short* WT = wt + m * 65536 + t * 256 + ci0;
    bfx8 o0, o1;
#pragma unroll
    for (int j = 0; j < 8; j++) {
        float gv = g ? g[ci0 + j] : 1.0f;
        o0[j] = f2bf(scale * gv * tile[j][t]);
    }
#pragma unroll
    for (int j = 0; j < 8; j++) {
        float gv = g ? g[ci0 + 8 + j] : 1.0f;
        o1[j] = f2bf(scale * gv * tile[8 + j][t]);
    }
    *reinterpret_cast<bfx8*>(WT) = o0;
    *reinterpret_cast<bfx8*>(WT + 8) = o1;
}

__global__ __launch_bounds__(256) void prep_b(
    const float* __restrict__ bq, const float* __restrict__ bk,
    const float* __restrict__ bv, const float* __restrict__ bp,
    const float* __restrict__ bbp, float* __restrict__ bb) {
    int m = blockIdx.x, t = threadIdx.x;
    const float* bias = (m == 0) ? bq : (m == 1) ? bk : (m == 2) ? bv : bp;
    float scale = (m == 0) ? 0.17677669529663687f : 1.0f;
    float s = bias[t];
#pragma unroll
    for (int i = 0; i < 16; i++) s += bbp[(m * 16 + i) * 256 + t];
    bb[m * 256 + t] = scale * s;
}

// ---------------- mega kernel: LN + qkv GEMM + attention + projection ----------------
// 512 blocks (b, chunk) x 512 threads (8 waves; wave = head = 32-col strip).
// Shared A slot (pitch 264): cva_hat -> xs_hat -> o_s.
// Per-wave 5120B scratch: q^T -> k^T -> V^T -> P^T halves -> trw epilogue.
// Attention in S^T orientation: S^T = mfma(K,Q^T); O^T = mfma(V^T,P^T).
__global__ __launch_bounds__(512, 4) void mega(const float* __restrict__ x,
                                               const float* __restrict__ cva,
                                               const short* __restrict__ wt,
                                               const float* __restrict__ bb,
                                               float* __restrict__ out) {
    int id = blockIdx.x;
    int b = id >> 6, ch = id & 63;
    int t = threadIdx.x, w = t >> 6, l = t & 63, c = l & 15, g = l >> 4;

    __shared__ short A[64 * 264];       // 33792 B
    __shared__ short scr_[8][2560];     // 40960 B (5120 B per wave)
    __shared__ float red[8][64][2];     // 4096 B
    short* S = scr_[w];

    const float* xb   = x + (size_t)b * 1048576 + ch * 64;
    const float* cvab = cva + (size_t)(b * 4096 + ch * 64) * 256;

    // ph1: LN over cva rows -> A (each wave 8 rows)
#pragma unroll
    for (int i = 0; i < 8; i++) {
        int row = w * 8 + i;
        float4 v = *reinterpret_cast<const float4*>(cvab + (size_t)row * 256 + l * 4);
        float s = v.x + v.y + v.z + v.w;
        float q2 = v.x * v.x + v.y * v.y + v.z * v.z + v.w * v.w;
#pragma unroll
        for (int m = 1; m < 64; m <<= 1) { s += __shfl_xor(s, m); q2 += __shfl_xor(q2, m); }
        float mean = s * (1.0f / 256.0f);
        float rstd = rsqrtf(q2 * (1.0f / 256.0f) - mean * mean + 1e-5f);
        bfx4 o;
        o[0] = f2bf((v.x - mean) * rstd);
        o[1] = f2bf((v.y - mean) * rstd);
        o[2] = f2bf((v.z - mean) * rstd);
        o[3] = f2bf((v.w - mean) * rstd);
        *reinterpret_cast<bfx4*>(A + row * 264 + l * 4) = o;
    }
    __syncthreads();  // bar0: cva_hat ready

    // ph2a: q GEMM -> qa (C-layout), weights streamed from global (L2)
    f32x4 qa[4][2] = {};
    {
        const short* w0 = wt + (size_t)(w * 32 + c) * 256 + g * 8;
        const short* w1 = w0 + 16 * 256;
#pragma unroll
        for (int ks = 0; ks < 8; ks++) {
            bfx8 af[4];
#pragma unroll
            for (int m = 0; m < 4; m++)
                af[m] = *reinterpret_cast<const bfx8*>(A + (m * 16 + c) * 264 + ks * 32 + g * 8);
            bfx8 q0 = *reinterpret_cast<const bfx8*>(w0 + ks * 32);
            bfx8 q1 = *reinterpret_cast<const bfx8*>(w1 + ks * 32);
#pragma unroll
            for (int m = 0; m < 4; m++) {
                qa[m][0] = MFMA16(af[m], q0, qa[m][0]);
                qa[m][1] = MFMA16(af[m], q1, qa[m][1]);
            }
        }
    }
    // transpose q through scratch [64 tok][pitch 40] -> qf (B-frag of Q^T)
    bfx8 qf[4];
    {
        float b0 = bb[w * 32 + c], b1 = bb[w * 32 + 16 + c];
#pragma unroll
        for (int m = 0; m < 4; m++)
#pragma unroll
            for (int j = 0; j < 4; j++) {
                S[(m * 16 + g * 4 + j) * 40 + c]      = f2bf(qa[m][0][j] + b0);
                S[(m * 16 + g * 4 + j) * 40 + 16 + c] = f2bf(qa[m][1][j] + b1);
            }
        LGKM0();
#pragma unroll
        for (int np = 0; np < 4; np++)
            qf[np] = *reinterpret_cast<const bfx8*>(S + (np * 16 + c) * 40 + g * 8);
        LGKM0();
    }

    // ph2b: k GEMM
    f32x4 ka[4][2] = {};
    {
        const short* w0 = wt + 65536 + (size_t)(w * 32 + c) * 256 + g * 8;
        const short* w1 = w0 + 16 * 256;
#pragma unroll
        for (int ks = 0; ks < 8; ks++) {
            bfx8 af[4];
#pragma unroll
            for (int m = 0; m < 4; m++)
                af[m] = *reinterpret_cast<const bfx8*>(A + (m * 16 + c) * 264 + ks * 32 + g * 8);
            bfx8 k0 = *reinterpret_cast<const bfx8*>(w0 + ks * 32);
            bfx8 k1 = *reinterpret_cast<const bfx8*>(w1 + ks * 32);
#pragma unroll
            for (int m = 0; m < 4; m++) {
                ka[m][0] = MFMA16(af[m], k0, ka[m][0]);
                ka[m][1] = MFMA16(af[m], k1, ka[m][1]);
            }
        }
    }

    // issue x column loads (latency hidden under k-transpose + bar1)
    float xg[32];
#pragma unroll
    for (int i = 0; i < 32; i++) xg[i] = xb[(size_t)(w * 32 + i) * 4096 + l];

    // transpose k -> kf (A-frag of K)
    bfx8 kf[4];
    {
        float b0 = bb[256 + w * 32 + c], b1 = bb[256 + w * 32 + 16 + c];
#pragma unroll
        for (int m = 0; m < 4; m++)
#pragma unroll
            for (int j = 0; j < 4; j++) {
                S[(m * 16 + g * 4 + j) * 40 + c]      = f2bf(ka[m][0][j] + b0);
                S[(m * 16 + g * 4 + j) * 40 + 16 + c] = f2bf(ka[m][1][j] + b1);
            }
        LGKM0();
#pragma unroll
        for (int m = 0; m < 4; m++)
            kf[m] = *reinterpret_cast<const bfx8*>(S + (m * 16 + c) * 40 + g * 8);
        LGKM0();
    }

    // x stats partials (token = l, c-slice = w*32..+32)
    {
        float s = 0.f, q2 = 0.f;
#pragma unroll
        for (int i = 0; i < 32; i++) { s += xg[i]; q2 += xg[i] * xg[i]; }
        red[w][l][0] = s;
        red[w][l][1] = q2;
    }
    __syncthreads();  // bar1: all cva_hat reads done, red ready

    float xmean, xrstd;
    {
        float s = 0.f, q2 = 0.f;
#pragma unroll
        for (int j2 = 0; j2 < 8; j2++) { s += red[j2][l][0]; q2 += red[j2][l][1]; }
        xmean = s * (1.0f / 256.0f);
        xrstd = rsqrtf(q2 * (1.0f / 256.0f) - xmean * xmean + 1e-5f);
    }

    // ph3: xs_hat -> A (row = token l, cols w*32..+32)
#pragma unroll
    for (int i2 = 0; i2 < 4; i2++) {
        bfx8 o;
#pragma unroll
        for (int jj = 0; jj < 8; jj++) o[jj] = f2bf((xg[i2 * 8 + jj] - xmean) * xrstd);
        *reinterpret_cast<bfx8*>(A + l * 264 + w * 32 + i2 * 8) = o;
    }
    __syncthreads();  // bar2: xs_hat ready

    // QK^T in S^T orientation: sa[m][np] = S^T[key 16m+4g+j][token 16np+c]
    f32x4 sa[4][4] = {};
#pragma unroll
    for (int m = 0; m < 4; m++)
#pragma unroll
        for (int np = 0; np < 4; np++)
            sa[m][np] = MFMA16(kf[m], qf[np], sa[m][np]);

    // softmax over keys (rows of S^T): 16 in-lane + 2 shfls per token tile
    float rs[4];
#pragma unroll
    for (int np = 0; np < 4; np++) {
        float mx = sa[0][np][0];
#pragma unroll
        for (int m = 0; m < 4; m++)
#pragma unroll
            for (int j = 0; j < 4; j++) mx = fmaxf(mx, sa[m][np][j]);
        mx = fmaxf(mx, __shfl_xor(mx, 16));
        mx = fmaxf(mx, __shfl_xor(mx, 32));
        float sum = 0.f;
#pragma unroll
        for (int m = 0; m < 4; m++)
#pragma unroll
            for (int j = 0; j < 4; j++) {
                float e = __expf(sa[m][np][j] - mx);
                sa[m][np][j] = e;
                sum += e;
            }
        sum += __shfl_xor(sum, 16);
        sum += __shfl_xor(sum, 32);
        rs[np] = 1.0f / sum;  // folded into O^T at the end
    }

    // pack P^T (unnormalized, <=1) to bf16 pairs in registers
    unsigned Pp[4][4][2];
#pragma unroll
    for (int m = 0; m < 4; m++)
#pragma unroll
        for (int np = 0; np < 4; np++) {
            Pp[m][np][0] = pk2(sa[m][np][0], sa[m][np][1]);
            Pp[m][np][1] = pk2(sa[m][np][2], sa[m][np][3]);
        }

    // ph4: v GEMM from A (xs_hat) -> va (C-layout)
    f32x4 va[4][2] = {};
    {
        const short* w0 = wt + 2 * 65536 + (size_t)(w * 32 + c) * 256 + g * 8;
        const short* w1 = w0 + 16 * 256;
#pragma unroll
        for (int ks = 0; ks < 8; ks++) {
            bfx8 af[4];
#pragma unroll
            for (int m = 0; m < 4; m++)
                af[m] = *reinterpret_cast<const bfx8*>(A + (m * 16 + c) * 264 + ks * 32 + g * 8);
            bfx8 v0 = *reinterpret_cast<const bfx8*>(w0 + ks * 32);
            bfx8 v1 = *reinterpret_cast<const bfx8*>(w1 + ks * 32);
#pragma unroll
            for (int m = 0; m < 4; m++) {
                va[m][0] = MFMA16(af[m], v0, va[m][0]);
                va[m][1] = MFMA16(af[m], v1, va[m][1]);
            }
        }
    }
    __syncthreads();  // bar3: all xs_hat reads done (o_s may be written later)

    // V transpose through scratch [32 d][pitch 72] -> vf (A-frag of V^T)
    bfx8 vf[2][2];
    {
        float b0 = bb[512 + w * 32 + c], b1 = bb[512 + w * 32 + 16 + c];
#pragma unroll
        for (int m = 0; m < 4; m++)
#pragma unroll
            for (int j = 0; j < 4; j++) {
                S[c * 72 + m * 16 + g * 4 + j]        = f2bf(va[m][0][j] + b0);
                S[(16 + c) * 72 + m * 16 + g * 4 + j] = f2bf(va[m][1][j] + b1);
            }
        LGKM0();
#pragma unroll
        for (int ks = 0; ks < 2; ks++)
#pragma unroll
            for (int mD = 0; mD < 2; mD++)
                vf[ks][mD] = *reinterpret_cast<const bfx8*>(S + (mD * 16 + c) * 72 + ks * 32 + g * 8);
        LGKM0();
    }

    // PV: O^T accumulate over two 32-key halves; P^T half through scratch [64][40]
    f32x4 oa[2][4] = {};
#pragma unroll
    for (int ks = 0; ks < 2; ks++) {
#pragma unroll
        for (int m2 = 0; m2 < 2; m2++)
#pragma unroll
            for (int np = 0; np < 4; np++) {
                *reinterpret_cast<unsigned*>(S + (np * 16 + c) * 40 + m2 * 16 + g * 4)     = Pp[ks * 2 + m2][np][0];
                *reinterpret_cast<unsigned*>(S + (np * 16 + c) * 40 + m2 * 16 + g * 4 + 2) = Pp[ks * 2 + m2][np][1];
            }
        LGKM0();
        bfx8 pf[4];
#pragma unroll
        for (int np = 0; np < 4; np++)
            pf[np] = *reinterpret_cast<const bfx8*>(S + (np * 16 + c) * 40 + g * 8);
        LGKM0();
#pragma unroll
        for (int mD = 0; mD < 2; mD++)
#pragma unroll
            for (int np = 0; np < 4; np++)
                oa[mD][np] = MFMA16(vf[ks][mD], pf[np], oa[mD][np]);
    }

    // o_s write (normalize by rs here): A[token][32w + d]
#pragma unroll
    for (int mD = 0; mD < 2; mD++)
#pragma unroll
        for (int np = 0; np < 4; np++) {
            bfx4 o4;
#pragma unroll
            for (int j = 0; j < 4; j++) o4[j] = f2bf(oa[mD][np][j] * rs[np]);
            *reinterpret_cast<bfx4*>(A + (np * 16 + c) * 264 + w * 32 + mD * 16 + g * 4) = o4;
        }
    __syncthreads();  // bar4: o_s ready

    // ph6: projection (wave = 32 output channels) + transposed fp32 store
    {
        f32x4 pa[4][2] = {};
        const short* w0 = wt + 3 * 65536 + (size_t)(w * 32 + c) * 256 + g * 8;
        const short* w1 = w0 + 16 * 256;
#pragma unroll
        for (int ks = 0; ks < 8; ks++) {
            bfx8 af[4];
#pragma unroll
            for (int m = 0; m < 4; m++)
                af[m] = *reinterpret_cast<const bfx8*>(A + (m * 16 + c) * 264 + ks * 32 + g * 8);
            bfx8 p0 = *reinterpret_cast<const bfx8*>(w0 + ks * 32);
            bfx8 p1 = *reinterpret_cast<const bfx8*>(w1 + ks * 32);
#pragma unroll
            for (int m = 0; m < 4; m++) {
                pa[m][0] = MFMA16(af[m], p0, pa[m][0]);
                pa[m][1] = MFMA16(af[m], p1, pa[m][1]);
            }
        }
        float* trw = reinterpret_cast<float*>(S);  // own scratch, 16x65 floats
        float* outb = out + (size_t)b * 1048576 + ch * 64;
#pragma unroll
        for (int p = 0; p < 2; p++) {
            float bvv = bb[768 + w * 32 + p * 16 + c];
#pragma unroll
            for (int m = 0; m < 4; m++)
#pragma unroll
                for (int j = 0; j < 4; j++)
                    trw[c * 65 + m * 16 + g * 4 + j] = pa[m][p][j] + bvv;
            LGKM0();
#pragma unroll
            for (int cl = 0; cl < 16; cl++) {
                int co = w * 32 + p * 16 + cl;
                outb[(size_t)co * 4096 + l] = trw[cl * 65 + l];
            }
            LGKM0();
        }
    }
}

extern "C" void kernel_launch(void* const* d_in, const int* in_sizes, int n_in,
                              void* d_out, int out_size, void* d_ws, size_t ws_size,
                              hipStream_t stream) {
    const float* x   = (const float*)d_in[0];
    const float* cva = (const float*)d_in[1];
    const float* qg  = (const float*)d_in[2];
    const float* qb  = (const float*)d_in[3];
    const float* kg  = (const float*)d_in[4];
    const float* kb  = (const float*)d_in[5];
    const float* vg  = (const float*)d_in[6];
    const float* vb  = (const float*)d_in[7];
    const float* Wq  = (const float*)d_in[8];
    const float* bq  = (const float*)d_in[9];
    const float* Wk  = (const float*)d_in[10];
    const float* bk  = (const float*)d_in[11];
    const float* Wv  = (const float*)d_in[12];
    const float* bv  = (const float*)d_in[13];
    const float* Wp  = (const float*)d_in[14];
    const float* bp  = (const float*)d_in[15];
    float* out = (float*)d_out;
    char* ws = (char*)d_ws;

    short* wt  = (short*)(ws);
    float* bb  = (float*)(ws + 4 * 65536 * sizeof(short));
    float* bbp = bb + 1024;

    prep_w<<<dim3(4, 16), 256, 0, stream>>>(Wq, Wk, Wv, Wp, qg, qb, kg, kb, vg, vb,
                                            wt, bbp);
    prep_b<<<4, 256, 0, stream>>>(bq, bk, bv, bp, bbp, bb);

    mega<<<512, 512, 0, stream>>>(x, cva, wt, bb, out);
}